// Round 5
// baseline (1899.954 us; speedup 1.0000x reference)
//
#include <hip/hip_runtime.h>
#include <hip/hip_fp16.h>

#define TT 512
#define BB 256
#define OBS 128
#define LAT 64
#define HID 256

typedef short bvec8 __attribute__((ext_vector_type(8)));
typedef float fvec4 __attribute__((ext_vector_type(4)));
typedef _Float16 hvec8 __attribute__((ext_vector_type(8)));
typedef _Float16 hvec4 __attribute__((ext_vector_type(4)));

__device__ __forceinline__ short f2bf(float f){
  union { float f; unsigned u; } v; v.f = f;
  unsigned u = v.u;
  return (short)((u + 0x7FFFu + ((u >> 16) & 1u)) >> 16);
}

// pack two f32 into one dword of 2 bf16 (RNE) — single VALU op
__device__ __forceinline__ unsigned cvt_pk_bf16(float lo, float hi){
  unsigned r;
  asm("v_cvt_pk_bf16_f32 %0, %1, %2" : "=v"(r) : "v"(lo), "v"(hi));
  return r;
}

__device__ __forceinline__ bvec8 cvt8(const float* __restrict__ p){
  const float4* q = (const float4*)p;
  float4 lo = q[0], hi = q[1];
  bvec8 r;
  r[0] = f2bf(lo.x); r[1] = f2bf(lo.y); r[2] = f2bf(lo.z); r[3] = f2bf(lo.w);
  r[4] = f2bf(hi.x); r[5] = f2bf(hi.y); r[6] = f2bf(hi.z); r[7] = f2bf(hi.w);
  return r;
}

__device__ __forceinline__ fvec4 mfma16(bvec8 a, bvec8 b, fvec4 c){
  return __builtin_amdgcn_mfma_f32_16x16x32_bf16(a, b, c, 0, 0, 0);
}

__device__ __forceinline__ float fast_rcp(float x){ return __builtin_amdgcn_rcpf(x); }

// LDS-producer/consumer barrier that does NOT drain vmcnt: global loads/stores
// stay in flight across it. ds ops drained via lgkmcnt(0).
__device__ __forceinline__ void lds_barrier(){
  asm volatile("s_waitcnt lgkmcnt(0)" ::: "memory");
  __builtin_amdgcn_s_barrier();
  asm volatile("" ::: "memory");
}

__global__ void cvt_kernel(const float* __restrict__ src, short* __restrict__ dst, int n){
  int i = blockIdx.x * 256 + threadIdx.x;
  if (i < n) dst[i] = f2bf(src[i]);
}

// cvt with k-permutation on the first KP columns: physical slot k holds the
// weight for logical col perm(k) = (k&~31) | ((k&31)>>1) | ((k&1)<<4).
// This pairs logical cols (j, j+16) at adjacent physical slots so the h/u
// producers can pack-write bf16x2. MFMA sums over k -> any consistent
// permutation of A-slots and B-slots is exact.
__global__ void cvtp_kernel(const float* __restrict__ src, short* __restrict__ dst,
                            int K, int KP){
  int k = blockIdx.x * 256 + threadIdx.x;
  int row = blockIdx.y;
  if (k >= K) return;
  int ksrc = (k < KP) ? ((k & ~31) | ((k & 31) >> 1) | ((k & 1) << 4)) : k;
  dst[(size_t)row*K + k] = f2bf(src[(size_t)row*K + ksrc]);
}

// ---------------------------------------------------------------------------
// gx precompute, consumer-swizzled (per gru thread contiguous):
// gxrz[rowq][tid(512)][16 halfs], gxn[rowq][tid(512)][8 halfs].
// Biases folded: r,z get b_ih+b_hh; n gets b_ih only.
// ---------------------------------------------------------------------------
__global__ __launch_bounds__(256) void gx_kernel(
    const float* __restrict__ x, const short* __restrict__ Wih_bf,
    const float* __restrict__ b_ih, const float* __restrict__ b_hh,
    __half* __restrict__ gxrz, __half* __restrict__ gxn)
{
  const int tid  = threadIdx.x;
  const int wave = tid >> 6;
  const int lane = tid & 63;
  const int quad = lane >> 4;
  const int nl   = lane & 15;
  const int rowbase = blockIdx.x * 64 + wave * 16;   // multiple of 16
  const int rowq    = rowbase >> 4;                  // = t*16 + wg

  bvec8 af[4];
#pragma unroll
  for (int ks = 0; ks < 4; ++ks)
    af[ks] = cvt8(x + (size_t)(rowbase + nl)*OBS + ks*32 + quad*8);

  for (int nt48 = 0; nt48 < 48; ++nt48){
    const int n = nt48*16 + nl;
    fvec4 acc = (fvec4)0.0f;
#pragma unroll
    for (int ks = 0; ks < 4; ++ks){
      bvec8 bw = *(const bvec8*)(Wih_bf + (size_t)n*OBS + ks*32 + quad*8);
      acc = mfma16(af[ks], bw, acc);
    }
    const int g   = nt48 >> 4;            // 0=r, 1=z, 2=n
    float bias = b_ih[n] + (g < 2 ? b_hh[n] : 0.0f);
    hvec4 s;
#pragma unroll
    for (int r = 0; r < 4; ++r) s[r] = (_Float16)(acc[r] + bias);
    const int wc  = (nt48 & 15) >> 1;     // consumer wave
    const int ntc = nt48 & 1;             // consumer nt
    const size_t tb = (size_t)rowq*512 + wc*64 + quad*16 + nl;
    if (g < 2) *(hvec4*)(gxrz + tb*16 + g*8 + ntc*4) = s;
    else       *(hvec4*)(gxn  + tb*8  + ntc*4)       = s;
  }
}

// ---------------------------------------------------------------------------
// u_pre for zscan, swizzled: usw[rowq][tid(512)][8 halfs]. pb1 folded.
// h_all is k-permuted; Pw1p's h-part is permuted to match.
// ---------------------------------------------------------------------------
__global__ __launch_bounds__(256) void upre_kernel(
    const short* __restrict__ h_all, const short* __restrict__ Pw1p,
    const float* __restrict__ pb1, __half* __restrict__ usw)
{
  const int tid  = threadIdx.x;
  const int wave = tid >> 6;
  const int lane = tid & 63;
  const int quad = lane >> 4;
  const int nl   = lane & 15;
  const int rowbase = (blockIdx.x * 4 + wave) * 32;
  const int rowq0   = rowbase >> 4;

  bvec8 af[2][8];
#pragma unroll
  for (int mt = 0; mt < 2; ++mt)
#pragma unroll
    for (int ks = 0; ks < 8; ++ks)
      af[mt][ks] = *(const bvec8*)(h_all + (size_t)(rowbase + mt*16 + nl)*HID + ks*32 + quad*8);

  for (int nt16 = 0; nt16 < 16; ++nt16){
    const int n = nt16*16 + nl;
    fvec4 acc[2];
    acc[0] = (fvec4)0.0f; acc[1] = (fvec4)0.0f;
#pragma unroll
    for (int ks = 0; ks < 8; ++ks){
      bvec8 bw = *(const bvec8*)(Pw1p + (size_t)n*320 + ks*32 + quad*8);
#pragma unroll
      for (int mt = 0; mt < 2; ++mt) acc[mt] = mfma16(af[mt][ks], bw, acc[mt]);
    }
    float bias = pb1[n];
    const int wc  = nt16 >> 1;
    const int ntc = nt16 & 1;
#pragma unroll
    for (int mt = 0; mt < 2; ++mt){
      hvec4 s;
#pragma unroll
      for (int r = 0; r < 4; ++r) s[r] = (_Float16)(acc[mt][r] + bias);
      const size_t tb = (size_t)(rowq0 + mt)*512 + wc*64 + quad*16 + nl;
      *(hvec4*)(usw + tb*8 + ntc*4) = s;
    }
  }
}

// ---------------------------------------------------------------------------
// GRU scan: 16 wgs x 512 threads; wg g owns samples [16g, 16g+16).
// Wave w owns gate-columns [32w, 32w+32) of r,z,n.
// VALU diet vs r4: k-permuted h layout -> cvt_pk_bf16 + 4 ds_write_b32 +
// 4 direct global stores (replaces 48 f2bf + 16 ds_write_b16 + loop-top
// ds_read/global_store + epilogue); running pointers (no per-step 64-bit
// muls); bnh folded into acc init; hn = ng + zg*(h-ng).
// ---------------------------------------------------------------------------
__attribute__((amdgpu_flat_work_group_size(512,512), amdgpu_waves_per_eu(2,2)))
__global__ void gru_kernel(
    const __half* __restrict__ gxrz, const __half* __restrict__ gxn,
    const short* __restrict__ Whh_bf,   // k-permuted
    const float* __restrict__ b_hh,
    short* __restrict__ h_all)          // k-permuted layout
{
  const int tid  = threadIdx.x;
  const int wave = tid >> 6;
  const int lane = tid & 63;
  const int quad = lane >> 4;
  const int nl   = lane & 15;
  const int b0   = blockIdx.x * 16;

  __shared__ __align__(16) short hA[2][16][264];
  __shared__ __align__(16) short WnL[4][2][8][512];  // [ks-4][nt][wave][lane*8]

  // ---- weights (B-frag layout: n=nl, k=quad*8+idx; physical k) ----
  bvec8 Whr[8][2], Whz[8][2], Whn[4][2];
  float bnh[2];
#pragma unroll
  for (int nt = 0; nt < 2; ++nt){
    const int j = wave*32 + nt*16 + nl;
#pragma unroll
    for (int ks = 0; ks < 8; ++ks){
      Whr[ks][nt] = *(const bvec8*)(Whh_bf + ((size_t)(0*HID + j))*HID + ks*32 + quad*8);
      Whz[ks][nt] = *(const bvec8*)(Whh_bf + ((size_t)(1*HID + j))*HID + ks*32 + quad*8);
    }
#pragma unroll
    for (int ks = 0; ks < 4; ++ks)
      Whn[ks][nt] = *(const bvec8*)(Whh_bf + ((size_t)(2*HID + j))*HID + ks*32 + quad*8);
#pragma unroll
    for (int ks = 4; ks < 8; ++ks){
      bvec8 w = *(const bvec8*)(Whh_bf + ((size_t)(2*HID + j))*HID + ks*32 + quad*8);
      *(bvec8*)&WnL[ks-4][nt][wave][lane*8] = w;
    }
    bnh[nt] = b_hh[2*HID + j];
  }

  float hreg[2][4];
#pragma unroll
  for (int nt = 0; nt < 2; ++nt)
#pragma unroll
    for (int r = 0; r < 4; ++r) hreg[nt][r] = 0.0f;

  // running per-thread pointers
  const size_t RZSTEP = (size_t)16*512*16;   // halfs per step
  const size_t NSTEP  = (size_t)16*512*8;
  const __half* grzp = gxrz + ((size_t)blockIdx.x*512 + tid)*16;
  const __half* gnp  = gxn  + ((size_t)blockIdx.x*512 + tid)*8;

  hvec8 grzA = *(const hvec8*)grzp;          // r-gate [nt*4+r]
  hvec8 grzB = *(const hvec8*)(grzp + 8);    // z-gate
  hvec8 gnA  = *(const hvec8*)gnp;           // n-gate
  grzp += RZSTEP; gnp += NSTEP;              // -> step 1

  const int cc2 = wave*32 + nl*2;            // physical col pair base
  short* hout = h_all + ((size_t)(b0 + quad*4))*HID + cc2;

  lds_barrier();

  for (int i = 0; i < TT; ++i){
    // acc init from prefetched gx; n-gate acc starts at bnh (C input of MFMA)
    fvec4 ar[2], az[2], anh_[2];
#pragma unroll
    for (int nt = 0; nt < 2; ++nt){
#pragma unroll
      for (int r = 0; r < 4; ++r){
        ar[nt][r] = (float)grzA[nt*4+r];
        az[nt][r] = (float)grzB[nt*4+r];
      }
      anh_[nt] = (fvec4)bnh[nt];
    }

    // issue next-step r,z prefetch (covered by MFMA + gate math)
    if (i + 1 < TT){
      grzA = *(const hvec8*)grzp;
      grzB = *(const hvec8*)(grzp + 8);
      grzp += RZSTEP;
    }

    // h-part MFMAs (K=256, physical k order)
    if (i > 0){
#pragma unroll
      for (int ks = 0; ks < 8; ++ks){
        bvec8 a = *(const bvec8*)&hA[i&1][nl][ks*32 + quad*8];
#pragma unroll
        for (int nt = 0; nt < 2; ++nt){
          ar[nt] = mfma16(a, Whr[ks][nt], ar[nt]);
          az[nt] = mfma16(a, Whz[ks][nt], az[nt]);
          if (ks < 4){
            anh_[nt] = mfma16(a, Whn[ks][nt], anh_[nt]);
          } else {
            bvec8 w = *(const bvec8*)&WnL[ks-4][nt][wave][lane*8];
            anh_[nt] = mfma16(a, w, anh_[nt]);
          }
        }
      }
    }

    // gate math; pack nt-pair per row -> 1 LDS dword + 1 global dword
#pragma unroll
    for (int rr = 0; rr < 4; ++rr){
      float rg0 = fast_rcp(1.0f + __expf(-ar[0][rr]));
      float zg0 = fast_rcp(1.0f + __expf(-az[0][rr]));
      float ng0 = 1.0f - 2.0f*fast_rcp(__expf(2.0f*((float)gnA[rr] + rg0*anh_[0][rr])) + 1.0f);
      float h0  = ng0 + zg0*(hreg[0][rr] - ng0);
      hreg[0][rr] = h0;

      float rg1 = fast_rcp(1.0f + __expf(-ar[1][rr]));
      float zg1 = fast_rcp(1.0f + __expf(-az[1][rr]));
      float ng1 = 1.0f - 2.0f*fast_rcp(__expf(2.0f*((float)gnA[4+rr] + rg1*anh_[1][rr])) + 1.0f);
      float h1  = ng1 + zg1*(hreg[1][rr] - ng1);
      hreg[1][rr] = h1;

      unsigned pk = cvt_pk_bf16(h0, h1);
      *(unsigned*)&hA[(i+1)&1][quad*4 + rr][cc2] = pk;     // LDS for next step
      *(unsigned*)(hout + (size_t)rr*HID) = pk;            // h_all[i] direct
    }
    hout += (size_t)BB*HID;

    // next-step n prefetch (after last use)
    if (i + 1 < TT){
      gnA = *(const hvec8*)gnp;
      gnp += NSTEP;
    }

    lds_barrier();   // lgkmcnt-only: gx loads + h stores stay in flight
  }
}

// ---------------------------------------------------------------------------
// z scan: 16 wgs x 512 threads, 2 barriers/step (was 3).
// stage1 (all 8 waves): au = u_pre + z_prev @ pW1z^T; relu; pack-write uA
//   (k-permuted, matches permuted Pw2p).
// stageB (waves 0-3 only, nt = {c, c+64}): post; z-math THREAD-LOCAL
//   (mean and logvar cols owned by same thread -> postL LDS removed).
// ---------------------------------------------------------------------------
__global__ __launch_bounds__(512) void zscan_kernel(
    const __half* __restrict__ usw, const float* __restrict__ eps,
    const short* __restrict__ Pw1p, const short* __restrict__ Pw2p,
    const float* __restrict__ pb2,
    short* __restrict__ z_all,
    float* __restrict__ post_mean, float* __restrict__ post_logvar)
{
  const int tid  = threadIdx.x;
  const int wave = tid >> 6;
  const int lane = tid & 63;
  const int quad = lane >> 4;
  const int nl   = lane & 15;
  const int b0   = blockIdx.x * 16;

  __shared__ __align__(16) short zA[2][16][72];
  __shared__ __align__(16) short uA[16][264];

  // stage1 weights: z-part of pW1 (k>=256, unpermuted region of Pw1p)
  bvec8 W1z[2][2];
#pragma unroll
  for (int nt = 0; nt < 2; ++nt){
    const int n = wave*32 + nt*16 + nl;
#pragma unroll
    for (int ks = 0; ks < 2; ++ks)
      W1z[ks][nt] = *(const bvec8*)(Pw1p + (size_t)n*320 + 256 + ks*32 + quad*8);
  }

  // stageB weights (waves 0-3): cols c = wave*16+nl and c+64
  bvec8 W2[8][2];
  float pb2m = 0.0f, pb2v = 0.0f;
  const int c = wave*16 + nl;   // valid for wave<4
  if (wave < 4){
#pragma unroll
    for (int nt2 = 0; nt2 < 2; ++nt2){
      const int n2 = nt2*64 + c;
#pragma unroll
      for (int ks = 0; ks < 8; ++ks)
        W2[ks][nt2] = *(const bvec8*)(Pw2p + (size_t)n2*HID + ks*32 + quad*8);
    }
    pb2m = pb2[c];
    pb2v = pb2[64 + c];
  }

  // running pointers
  const size_t USTEP = (size_t)16*512*8;
  const __half* ub = usw + ((size_t)blockIdx.x*512 + tid)*8;
  hvec8 upf = *(const hvec8*)ub;
  ub += USTEP;

  const float* epsb = eps + ((size_t)(b0 + quad*4))*LAT + c;
  float*  pmb = post_mean   + ((size_t)(b0 + quad*4))*LAT + c;
  float*  pvb = post_logvar + ((size_t)(b0 + quad*4))*LAT + c;
  short*  zob = z_all       + ((size_t)(b0 + quad*4))*LAT + c;

  float ef[4];
  if (wave < 4){
#pragma unroll
    for (int rr = 0; rr < 4; ++rr) ef[rr] = epsb[rr*LAT];
    epsb += (size_t)BB*LAT;
  }

  const int cc2u = wave*32 + nl*2;

  for (int i = 0; i < TT; ++i){
    // ---- stage1: au = u_pre (+ z_prev @ W1z) ----
    fvec4 au[2];
#pragma unroll
    for (int nt = 0; nt < 2; ++nt)
#pragma unroll
      for (int r = 0; r < 4; ++r)
        au[nt][r] = (float)upf[nt*4+r];

    if (i + 1 < TT){
      upf = *(const hvec8*)ub;
      ub += USTEP;
    }

    if (i > 0){
#pragma unroll
      for (int ks = 0; ks < 2; ++ks){
        bvec8 a = *(const bvec8*)&zA[i&1][nl][ks*32 + quad*8];
#pragma unroll
        for (int nt = 0; nt < 2; ++nt) au[nt] = mfma16(a, W1z[ks][nt], au[nt]);
      }
    }
    // relu + pack-write uA (permuted layout)
#pragma unroll
    for (int r = 0; r < 4; ++r){
      float u0 = au[0][r] > 0.0f ? au[0][r] : 0.0f;
      float u1 = au[1][r] > 0.0f ? au[1][r] : 0.0f;
      *(unsigned*)&uA[quad*4 + r][cc2u] = cvt_pk_bf16(u0, u1);
    }
    lds_barrier();

    // ---- stageB + z math (waves 0-3) ----
    if (wave < 4){
      fvec4 ap[2];
      ap[0] = (fvec4)0.0f; ap[1] = (fvec4)0.0f;
#pragma unroll
      for (int ks = 0; ks < 8; ++ks){
        bvec8 a = *(const bvec8*)&uA[nl][ks*32 + quad*8];
        ap[0] = mfma16(a, W2[ks][0], ap[0]);
        ap[1] = mfma16(a, W2[ks][1], ap[1]);
      }
#pragma unroll
      for (int rr = 0; rr < 4; ++rr){
        float mean = ap[0][rr] + pb2m;
        float lv   = ap[1][rr] + pb2v;
        float z    = mean + ef[rr]*__expf(0.5f*lv);
        short zb   = f2bf(z);
        pmb[rr*LAT] = mean;
        pvb[rr*LAT] = lv;
        zob[rr*LAT] = zb;
        zA[(i+1)&1][quad*4 + rr][c] = zb;
      }
      pmb += (size_t)BB*LAT; pvb += (size_t)BB*LAT; zob += (size_t)BB*LAT;
      if (i + 1 < TT){
#pragma unroll
        for (int rr = 0; rr < 4; ++rr) ef[rr] = epsb[rr*LAT];
        epsb += (size_t)BB*LAT;
      }
    }
    lds_barrier();
  }
}

// ---------------------------------------------------------------------------
// Tail: prior (from z_{t-1}) and decoder (from z_t), parallel over (p,t,mblk).
// ---------------------------------------------------------------------------
__global__ __launch_bounds__(256) void tail_kernel(
    const short* __restrict__ z_all,
    const short* __restrict__ Tw1, const short* __restrict__ Tw2,
    const short* __restrict__ Dw1, const short* __restrict__ Dw2,
    const float* __restrict__ tb1, const float* __restrict__ tb2,
    const float* __restrict__ db1, const float* __restrict__ db2,
    float* __restrict__ prior_mean, float* __restrict__ prior_logvar,
    float* __restrict__ recons)
{
  const int tid  = threadIdx.x;
  const int wave = tid >> 6;
  const int lane = tid & 63;
  const int quad = lane >> 4;
  const int nl   = lane & 15;
  const int wg   = blockIdx.x;
  const int p    = wg >> 11;        // 0 = prior, 1 = decoder
  const int t    = (wg >> 2) & 511;
  const int mb   = wg & 3;          // 64-sample block

  const short* W1 = p ? Dw1 : Tw1;
  const short* W2 = p ? Dw2 : Tw2;
  const float* B1 = p ? db1 : tb1;
  const float* B2 = p ? db2 : tb2;

  __shared__ __align__(16) short u1[64][264];
  __shared__ float b1s[HID], b2s[OBS];

  b1s[tid] = B1[tid];
  if (tid < OBS) b2s[tid] = B2[tid];
  __syncthreads();

  const bool zzero = (p == 0 && t == 0);
  const int  tz    = p ? t : (t - 1);
  const short* zsrc = z_all + (((size_t)(zzero ? 0 : tz))*BB + mb*64)*LAT;

  // layer 1: M=64, N=256, K=64
  fvec4 acc1[4][4];
  for (int a = 0; a < 4; ++a) for (int b = 0; b < 4; ++b) acc1[a][b] = (fvec4)0.0f;
  for (int ks = 0; ks < 2; ++ks){
    bvec8 af[4];
    for (int mt = 0; mt < 4; ++mt){
      if (zzero) af[mt] = (bvec8)(short)0;
      else af[mt] = *(const bvec8*)(zsrc + (mt*16 + nl)*LAT + ks*32 + quad*8);
    }
    for (int nt = 0; nt < 4; ++nt){
      int n = (wave*4 + nt)*16 + nl;
      bvec8 bw = *(const bvec8*)(W1 + n*LAT + ks*32 + quad*8);
      for (int mt = 0; mt < 4; ++mt) acc1[mt][nt] = mfma16(af[mt], bw, acc1[mt][nt]);
    }
  }
  for (int nt = 0; nt < 4; ++nt){
    int n = (wave*4 + nt)*16 + nl;
    float bias = b1s[n];
    for (int mt = 0; mt < 4; ++mt)
      for (int r = 0; r < 4; ++r){
        float v = acc1[mt][nt][r] + bias;
        u1[mt*16 + quad*4 + r][n] = f2bf(v > 0.0f ? v : 0.0f);
      }
  }
  __syncthreads();

  // layer 2: M=64, N=128, K=256
  fvec4 acc2[4][2];
  for (int a = 0; a < 4; ++a) for (int b = 0; b < 2; ++b) acc2[a][b] = (fvec4)0.0f;
  for (int ks = 0; ks < 8; ++ks){
    bvec8 af[4];
    for (int mt = 0; mt < 4; ++mt)
      af[mt] = *(const bvec8*)(&u1[mt*16 + nl][ks*32 + quad*8]);
    for (int nt = 0; nt < 2; ++nt){
      int n = (wave*2 + nt)*16 + nl;
      bvec8 bw = *(const bvec8*)(W2 + n*HID + ks*32 + quad*8);
      for (int mt = 0; mt < 4; ++mt) acc2[mt][nt] = mfma16(af[mt], bw, acc2[mt][nt]);
    }
  }
  for (int nt = 0; nt < 2; ++nt){
    int n = (wave*2 + nt)*16 + nl;
    float bias = b2s[n];
    for (int mt = 0; mt < 4; ++mt)
      for (int r = 0; r < 4; ++r){
        int b = mb*64 + mt*16 + quad*4 + r;
        size_t row = (size_t)t*BB + b;
        float v = acc2[mt][nt][r] + bias;
        if (p) recons[row*OBS + n] = v;
        else if (n < LAT) prior_mean[row*LAT + n] = v;
        else              prior_logvar[row*LAT + (n - LAT)] = v;
      }
  }
}

extern "C" void kernel_launch(void* const* d_in, const int* in_sizes, int n_in,
                              void* d_out, int out_size, void* d_ws, size_t ws_size,
                              hipStream_t stream) {
  const float* x    = (const float*)d_in[0];
  const float* eps  = (const float*)d_in[1];
  const float* W_ih = (const float*)d_in[2];
  const float* W_hh = (const float*)d_in[3];
  const float* b_ih = (const float*)d_in[4];
  const float* b_hh = (const float*)d_in[5];
  const float* tW1  = (const float*)d_in[6];
  const float* tb1  = (const float*)d_in[7];
  const float* tW2  = (const float*)d_in[8];
  const float* tb2  = (const float*)d_in[9];
  const float* pW1  = (const float*)d_in[10];
  const float* pb1  = (const float*)d_in[11];
  const float* pW2  = (const float*)d_in[12];
  const float* pb2  = (const float*)d_in[13];
  const float* dW1  = (const float*)d_in[14];
  const float* db1  = (const float*)d_in[15];
  const float* dW2  = (const float*)d_in[16];
  const float* db2  = (const float*)d_in[17];

  float* out          = (float*)d_out;
  float* recons       = out;                 // 512*256*128
  float* prior_mean   = out + 16777216;      // 512*256*64
  float* prior_logvar = out + 25165824;
  float* post_mean    = out + 33554432;
  float* post_logvar  = out + 41943040;

  char* ws = (char*)d_ws;
  short* h_all = (short*)ws;                         // 512*256*256 bf16 = 67,108,864 B
  short* z_all = (short*)(ws + 67108864);            // 512*256*64  bf16 = 16,777,216 B
  short* wts   = (short*)(ws + 67108864 + 16777216);
  short* Pw1 = wts;                  // 81920   (k-permuted h-part)
  short* Pw2 = Pw1 + 81920;          // 32768   (k-permuted)
  short* Tw1 = Pw2 + 32768;          // 16384
  short* Tw2 = Tw1 + 16384;          // 32768
  short* Dw1 = Tw2 + 32768;          // 16384
  short* Dw2 = Dw1 + 16384;          // 32768
  short* Wih_bf = Dw2 + 32768;       // 98304  (768 x 128)
  short* Whh_bf = Wih_bf + 98304;    // 196608 (768 x 256, k-permuted)

  // gx scratch (swizzled): 201,326,592 B == out_size exactly; dead after gru.
  // usw scratch: 67,108,864 B == recons region; written after gru, read by
  // zscan, overwritten by tail afterwards.
  __half* gxrz = (__half*)d_out;
  __half* gxn  = (__half*)d_out + 67108864;   // +134,217,728 B
  __half* usw  = (__half*)d_out;

  cvtp_kernel<<<dim3(2,256), 256, 0, stream>>>(pW1, Pw1, 320, 256);
  cvtp_kernel<<<dim3(1,128), 256, 0, stream>>>(pW2, Pw2, 256, 256);
  cvtp_kernel<<<dim3(1,768), 256, 0, stream>>>(W_hh, Whh_bf, 256, 256);
  cvt_kernel<<<(16384+255)/256, 256, 0, stream>>>(tW1, Tw1, 16384);
  cvt_kernel<<<(32768+255)/256, 256, 0, stream>>>(tW2, Tw2, 32768);
  cvt_kernel<<<(16384+255)/256, 256, 0, stream>>>(dW1, Dw1, 16384);
  cvt_kernel<<<(32768+255)/256, 256, 0, stream>>>(dW2, Dw2, 32768);
  cvt_kernel<<<(98304+255)/256, 256, 0, stream>>>(W_ih, Wih_bf, 98304);

  gx_kernel<<<2048, 256, 0, stream>>>(x, Wih_bf, b_ih, b_hh, gxrz, gxn);
  gru_kernel<<<16, 512, 0, stream>>>(gxrz, gxn, Whh_bf, b_hh, h_all);
  upre_kernel<<<1024, 256, 0, stream>>>(h_all, Pw1, pb1, usw);
  zscan_kernel<<<16, 512, 0, stream>>>(usw, eps, Pw1, Pw2, pb2,
                                       z_all, post_mean, post_logvar);
  tail_kernel<<<4096, 256, 0, stream>>>(z_all, Tw1, Tw2, Dw1, Dw2,
                                        tb1, tb2, db1, db2,
                                        prior_mean, prior_logvar, recons);
}